// Round 8
// baseline (214.000 us; speedup 1.0000x reference)
//
#include <hip/hip_runtime.h>
#include <hip/hip_bf16.h>
#include <math.h>

// Masked dot-product attention, round 8: BARRIER-FREE wave-private flash.
// Rounds 5-7 were pinned at ~96us: compiler emits s_waitcnt vmcnt(0) before
// every s_barrier, so the "prefetch across the barrier" never pipelined and
// each tile paid full memory latency serially. Fix: no LDS, no __syncthreads.
// Each wave (32 q rows) loads K straight into A-frags (K rows == A-layout)
// and V^T A-frags via coalesced per-lane column reads; compiler inserts
// partial vmcnt waits -> loads pipeline across tiles, waves drift freely.
// Math identical to round 7 (fixed-m exp2 softmax, shuffle P^T frags,
// split-K with direct write for single-chunk batches).

#define B_    32
#define LQ_   2048
#define LK_   2048
#define D_    64
#define SLOTW (32 * 64 + 32)    // per wave-slot: O^T (32q x 64d) + l(32)
#define MBIAS 16.0f

typedef __attribute__((ext_vector_type(8)))  short bf16x8;
typedef __attribute__((ext_vector_type(4)))  float f32x4;
typedef __attribute__((ext_vector_type(16))) float f32x16;

#if defined(__has_builtin) && __has_builtin(__builtin_amdgcn_exp2f)
#define EXP2(x) __builtin_amdgcn_exp2f(x)
#else
#define EXP2(x) exp2f(x)
#endif

static __device__ __forceinline__ unsigned pk_bf16(float a, float b) {
    __hip_bfloat162 h = __float22bfloat162_rn(float2{a, b});
    return *(unsigned*)&h;
}

__global__ __launch_bounds__(256, 2) void fa_stage1(
    const float* __restrict__ Q, const float* __restrict__ K,
    const float* __restrict__ V, const int* __restrict__ vlen,
    float* __restrict__ O, float* __restrict__ ws,
    int nchunks, int chunk_len)
{
    const int tid  = threadIdx.x;
    const int wave = tid >> 6;
    const int lane = tid & 63;
    const int c31  = lane & 31;
    const int h    = lane >> 5;

    const int b = blockIdx.y, cidx = blockIdx.z;
    const int vl = vlen[b];
    const int k_begin = cidx * chunk_len;
    if (k_begin >= vl) return;                    // block-uniform early exit
    const int k_end = min(k_begin + chunk_len, vl);
    const int nt = (k_end - k_begin + 63) >> 6;
    const int q0 = blockIdx.x * 128 + wave * 32;  // 32 q rows per wave
    const int qw = q0 >> 5;                       // wave-slot index
    const int direct = (vl <= chunk_len);

    const float qscale = 0.125f * 1.44269504088896340736f;  // 1/8 * log2(e)

    // ---- Q B-frags: B[k=dim][n=q], dim = ks*16 + h*8 + j, q = c31 ----
    unsigned qfrag[4][4];
#pragma unroll
    for (int ks = 0; ks < 4; ++ks) {
        const float* qp = Q + ((size_t)(b * LQ_ + q0 + c31)) * D_ + ks * 16 + h * 8;
        f32x4 t0 = *(const f32x4*)qp;
        f32x4 t1 = *(const f32x4*)(qp + 4);
#pragma unroll
        for (int jj = 0; jj < 2; ++jj) {
            qfrag[ks][jj]     = pk_bf16(t0[2*jj] * qscale, t0[2*jj+1] * qscale);
            qfrag[ks][jj + 2] = pk_bf16(t1[2*jj] * qscale, t1[2*jj+1] * qscale);
        }
    }

    f32x16 oacc[2];   // O^T: row dim = dt*32 + (r&3)+8*(r>>2)+4h, col q = c31
#pragma unroll
    for (int dt = 0; dt < 2; ++dt)
#pragma unroll
        for (int r = 0; r < 16; ++r) oacc[dt][r] = 0.f;
    float lrun = 0.f;

    for (int t = 0; t < nt; ++t) {
        const int k0 = k_begin + t * 64;

        // ---- S^T = K*Q^T - 16 : K A-frags straight from global.
        // A[m=key s*32+c31][k=dim ks*16+h*8+j] = K[b][k0+s*32+c31][...]
        f32x16 st[2];
        const float* krow = K + ((size_t)(b * LK_ + k0 + c31)) * D_ + h * 8;
#pragma unroll
        for (int s = 0; s < 2; ++s) {
#pragma unroll
            for (int r = 0; r < 16; ++r) st[s][r] = -MBIAS;
            const float* kp = krow + (size_t)s * 32 * D_;
#pragma unroll
            for (int ks = 0; ks < 4; ++ks) {
                f32x4 a0 = *(const f32x4*)(kp + ks * 16);
                f32x4 a1 = *(const f32x4*)(kp + ks * 16 + 4);
                unsigned kw[4] = { pk_bf16(a0[0], a0[1]), pk_bf16(a0[2], a0[3]),
                                   pk_bf16(a1[0], a1[1]), pk_bf16(a1[2], a1[3]) };
                st[s] = __builtin_amdgcn_mfma_f32_32x32x16_bf16(
                    *(const bf16x8*)kw, *(const bf16x8*)&qfrag[ks][0], st[s], 0, 0, 0);
            }
        }

        // ---- mask tail keys >= vl ----
        if (k0 + 64 > vl) {
#pragma unroll
            for (int s = 0; s < 2; ++s) {
                const int base = k0 + s * 32 + 4 * h;
#pragma unroll
                for (int r = 0; r < 16; ++r) {
                    const int key = base + (r & 3) + 8 * (r >> 2);
                    if (key >= vl) st[s][r] = -1e30f;
                }
            }
        }

        // ---- fixed-m softmax: p = exp2(st), row-sum into lrun ----
        float rs0 = 0.f, rs1 = 0.f, rs2 = 0.f, rs3 = 0.f;
#pragma unroll
        for (int s = 0; s < 2; ++s)
#pragma unroll
            for (int g = 0; g < 4; ++g) {
                float p0 = EXP2(st[s][4*g]);
                float p1 = EXP2(st[s][4*g+1]);
                float p2 = EXP2(st[s][4*g+2]);
                float p3 = EXP2(st[s][4*g+3]);
                st[s][4*g] = p0; st[s][4*g+1] = p1; st[s][4*g+2] = p2; st[s][4*g+3] = p3;
                rs0 += p0; rs1 += p1; rs2 += p2; rs3 += p3;
            }
        float rs = (rs0 + rs1) + (rs2 + rs3);
        rs += __shfl_xor(rs, 32);
        lrun += rs;

        // ---- pack P pairs ----
        unsigned pk[2][8];
#pragma unroll
        for (int s = 0; s < 2; ++s)
#pragma unroll
            for (int m = 0; m < 8; ++m)
                pk[s][m] = pk_bf16(st[s][2 * m], st[s][2 * m + 1]);

        // ---- O^T += V^T * P^T : V^T A-frags straight from global.
        // A[m=dim dt*32+c31][k=key kq*16+h*8+j] = V[b][k0+kq*16+h*8+j][dt*32+c31]
#pragma unroll
        for (int kq = 0; kq < 4; ++kq) {
            const float* vp = V + ((size_t)(b * LK_ + k0 + kq * 16 + h * 8)) * D_ + c31;
            float v0[8], v1[8];
#pragma unroll
            for (int j = 0; j < 8; ++j) {
                v0[j] = vp[(size_t)j * D_];
                v1[j] = vp[(size_t)j * D_ + 32];
            }
            unsigned vw0[4], vw1[4];
#pragma unroll
            for (int jj = 0; jj < 4; ++jj) {
                vw0[jj] = pk_bf16(v0[2*jj], v0[2*jj+1]);
                vw1[jj] = pk_bf16(v1[2*jj], v1[2*jj+1]);
            }

            const int s = kq >> 1, A4 = (kq & 1) * 4;
            unsigned p0 = pk[s][A4], p1 = pk[s][A4+1], p2 = pk[s][A4+2], p3 = pk[s][A4+3];
            unsigned xp0 = __shfl_xor((int)p0, 32);
            unsigned xp1 = __shfl_xor((int)p1, 32);
            unsigned xp2 = __shfl_xor((int)p2, 32);
            unsigned xp3 = __shfl_xor((int)p3, 32);
            unsigned pf[4];
            pf[0] = h ? xp2 : p0;
            pf[1] = h ? xp3 : p1;
            pf[2] = h ? p2  : xp0;
            pf[3] = h ? p3  : xp1;
            const bf16x8 pfr = *(const bf16x8*)&pf[0];

            oacc[0] = __builtin_amdgcn_mfma_f32_32x32x16_bf16(
                *(const bf16x8*)vw0, pfr, oacc[0], 0, 0, 0);
            oacc[1] = __builtin_amdgcn_mfma_f32_32x32x16_bf16(
                *(const bf16x8*)vw1, pfr, oacc[1], 0, 0, 0);
        }
    }

    // ---- epilogue ----
    if (direct) {
        const float inv = 1.f / lrun;
        float* op = O + ((size_t)(b * LQ_ + q0 + c31)) * D_;
#pragma unroll
        for (int dt = 0; dt < 2; ++dt)
#pragma unroll
            for (int g = 0; g < 4; ++g) {
                f32x4 v;
#pragma unroll
                for (int j = 0; j < 4; ++j) v[j] = oacc[dt][4 * g + j] * inv;
                *(f32x4*)(op + dt * 32 + 8 * g + 4 * h) = v;
            }
    } else {
        float* base = ws + (size_t)((b * 64 + qw) * nchunks + cidx) * SLOTW;
        float* pp = base + (size_t)c31 * D_;
#pragma unroll
        for (int dt = 0; dt < 2; ++dt)
#pragma unroll
            for (int g = 0; g < 4; ++g) {
                f32x4 v;
#pragma unroll
                for (int j = 0; j < 4; ++j) v[j] = oacc[dt][4 * g + j];
                *(f32x4*)(pp + dt * 32 + 8 * g + 4 * h) = v;
            }
        if (h == 0)
            base[32 * 64 + c31] = lrun;
    }
}

__global__ __launch_bounds__(256) void fa_combine(
    const float* __restrict__ ws, const int* __restrict__ vlen,
    float* __restrict__ O, int nchunks, int chunk_len)
{
    const int idx = blockIdx.x * 256 + threadIdx.x;   // B*LQ*16 threads
    const int b  = idx >> 15;            // LQ*16 = 32768 per batch
    const int vl = vlen[b];
    if (vl <= chunk_len) return;         // stage1 wrote O directly
    const int r  = idx & 32767;
    const int q  = r >> 4;
    const int dg = r & 15;
    const int nc = min(nchunks, (vl + chunk_len - 1) / chunk_len);
    const int qw = q >> 5, ql = q & 31;
    const size_t sbase = (size_t)((b * 64 + qw) * nchunks) * SLOTW;

    // fixed m across chunks -> plain sums
    f32x4 acc = (f32x4){0.f, 0.f, 0.f, 0.f};
    float L = 0.f;
    for (int c = 0; c < nc; ++c) {
        const float* sb = ws + sbase + (size_t)c * SLOTW;
        L += sb[32 * 64 + ql];
        f32x4 o4 = *(const f32x4*)(sb + (size_t)ql * D_ + dg * 4);
        acc += o4;
    }
    const float inv = 1.f / L;
    *(f32x4*)(O + (size_t)(b * LQ_ + q) * D_ + dg * 4) = acc * inv;
}

extern "C" void kernel_launch(void* const* d_in, const int* in_sizes, int n_in,
                              void* d_out, int out_size, void* d_ws, size_t ws_size,
                              hipStream_t stream) {
    const float* Q    = (const float*)d_in[0];
    const float* K    = (const float*)d_in[1];
    const float* V    = (const float*)d_in[2];
    const int*   vlen = (const int*)d_in[3];
    float*       O    = (float*)d_out;
    float*       ws   = (float*)d_ws;

    // largest split whose partials fit the workspace (S=1 -> all direct)
    int S = 4;
    while (S > 1 && (size_t)B_ * 64 * S * SLOTW * 4 > ws_size) S >>= 1;
    const int chunk_len = LK_ / S;

    dim3 grid(LQ_ / 128, B_, S);
    fa_stage1<<<grid, dim3(256), 0, stream>>>(Q, K, V, vlen, O, ws, S, chunk_len);
    if (S > 1) {
        const int nthreads = B_ * LQ_ * 16;
        fa_combine<<<dim3(nthreads / 256), dim3(256), 0, stream>>>(ws, vlen, O, S, chunk_len);
    }
}